// Round 2
// baseline (189.378 us; speedup 1.0000x reference)
//
#include <hip/hip_runtime.h>

// out(b,l,h) = data(b,l,h) * mask(b,l); B=512, L=512, H=100, C=40.
// mask: aE = aI+aL;  l<aE -> 1-(aE-l)/C;  else l<sL -> 1-(l-aI)/C;  else 0.
//
// Round-2 change (single variable vs round 1): NORMAL loads/stores instead
// of nontemporal. Theory: NT stores stream synchronously to HBM (no-allocate)
// so the kernel can't retire until 105 MB drains at HBM speed; NT loads keep
// `data` from ever becoming L3-resident across bench iterations. Normal
// full-line stores complete at L2/L3 (write-back, no RFO) and `data`
// (105 MB < 256 MB L3) stays cache-resident across iterations.
//
// Kept from round 1:
//  - mask == 0 exactly when l >= max(aE, sL) (~49% of rows) -> skip the read.
//  - one block per (b, half): aI/aE/sL block-uniform -> scalar loads.
//  - 25 exact iterations/thread (6400/256), unroll 5.

constexpr int kL        = 512;
constexpr int kF4PerRow = 25;                 // H=100 floats = 25 float4
constexpr int kF4PerB   = kL * kF4PerRow;     // 12800 float4 per b
constexpr int kChunkF4  = kF4PerB / 2;        // 6400: half of one b per block
constexpr float kInvC   = 1.0f / 40.0f;

typedef float f32x4 __attribute__((ext_vector_type(4)));

__global__ __launch_bounds__(256, 4) void mask_mul_kernel(
    const f32x4* __restrict__ data,
    const int* __restrict__ a_idx,
    const int* __restrict__ a_len,
    const int* __restrict__ s_len,
    f32x4* __restrict__ out)
{
    const int b     = blockIdx.x >> 1;        // uniform -> SGPR
    const int chunk = blockIdx.x & 1;

    const int aI = a_idx[b];
    const int aE = aI + a_len[b];
    const int sL = s_len[b];
    const int zs = max(aE, sL);               // rows >= zs are exactly zero

    const int base4 = b * kF4PerB + chunk * kChunkF4; // first float4 of block
    const int l0    = chunk * (kL / 2);               // first row of block

    #pragma unroll 5
    for (int i = threadIdx.x; i < kChunkF4; i += 256) {  // exactly 25 iters
        const int idx4 = base4 + i;
        const int l    = l0 + (int)((unsigned)i / 25u);  // row (magic-mul)

        float m;
        if (l < aE)       m = 1.0f - (float)(aE - l) * kInvC;
        else if (l < sL)  m = 1.0f - (float)(l - aI) * kInvC;
        else              m = 0.0f;

        f32x4 v = {0.0f, 0.0f, 0.0f, 0.0f};
        if (l < zs) {                         // zero rows: no read at all
            v = data[idx4];                   // normal cached load
            v *= m;
        }
        out[idx4] = v;                        // normal cached store
    }
}

extern "C" void kernel_launch(void* const* d_in, const int* in_sizes, int n_in,
                              void* d_out, int out_size, void* d_ws, size_t ws_size,
                              hipStream_t stream) {
    const float* data = (const float*)d_in[0];
    const int* a_idx  = (const int*)d_in[1];
    const int* a_len  = (const int*)d_in[2];
    const int* s_len  = (const int*)d_in[3];
    float* out        = (float*)d_out;

    const int B = out_size / (kL * 100);      // 512
    const int blocks = B * 2;                 // 1024: one per (b, half)
    const int threads = 256;

    mask_mul_kernel<<<blocks, threads, 0, stream>>>(
        (const f32x4*)data, a_idx, a_len, s_len, (f32x4*)out);
}

// Round 3
// 179.069 us; speedup vs baseline: 1.0576x; 1.0576x over previous
//
#include <hip/hip_runtime.h>

// out(b,l,h) = data(b,l,h) * mask(b,l); B=512, L=512, H=100, C=40.
// mask: aE = aI+aL;  l<aE -> 1-(aE-l)/C;  else l<sL -> 1-(l-aI)/C;  else 0.
//
// FINAL (revert to round-1 NT version — best measured, 179.4 µs).
// Session evidence:
//  - Timed region = 2× 419 MB harness poison-fills (~125 µs @ 84% HBM peak,
//    untouchable) + this kernel (~25-30 µs) + reset memsets.
//  - NT stores are REQUIRED: cached stores leave dirty lines that slow the
//    harness fills 6.7 -> 6.15 TB/s (round 2: +10 µs total regression).
//  - Kernel is at its store-drain floor: 105 MB mandatory output writes;
//    read-skip (-52 MB) and 100x parallelism changes all move <1 µs.
//
// Structure:
//  - mask == 0 exactly when l >= max(aE, sL) (~49% of rows) -> skip the read.
//  - one block per (b, half): aI/aE/sL block-uniform -> scalar loads.
//  - 25 exact iterations/thread (6400/256), unroll 5.

constexpr int kL        = 512;
constexpr int kF4PerRow = 25;                 // H=100 floats = 25 float4
constexpr int kF4PerB   = kL * kF4PerRow;     // 12800 float4 per b
constexpr int kChunkF4  = kF4PerB / 2;        // 6400: half of one b per block
constexpr float kInvC   = 1.0f / 40.0f;

typedef float f32x4 __attribute__((ext_vector_type(4)));

__global__ __launch_bounds__(256, 4) void mask_mul_kernel(
    const f32x4* __restrict__ data,
    const int* __restrict__ a_idx,
    const int* __restrict__ a_len,
    const int* __restrict__ s_len,
    f32x4* __restrict__ out)
{
    const int b     = blockIdx.x >> 1;        // uniform -> SGPR
    const int chunk = blockIdx.x & 1;

    const int aI = a_idx[b];
    const int aE = aI + a_len[b];
    const int sL = s_len[b];
    const int zs = max(aE, sL);               // rows >= zs are exactly zero

    const int base4 = b * kF4PerB + chunk * kChunkF4; // first float4 of block
    const int l0    = chunk * (kL / 2);               // first row of block

    #pragma unroll 5
    for (int i = threadIdx.x; i < kChunkF4; i += 256) {  // exactly 25 iters
        const int idx4 = base4 + i;
        const int l    = l0 + (int)((unsigned)i / 25u);  // row (magic-mul)

        float m;
        if (l < aE)       m = 1.0f - (float)(aE - l) * kInvC;
        else if (l < sL)  m = 1.0f - (float)(l - aI) * kInvC;
        else              m = 0.0f;

        f32x4 v = {0.0f, 0.0f, 0.0f, 0.0f};
        if (l < zs) {                         // zero rows: no read at all
            v = __builtin_nontemporal_load(&data[idx4]);
            v *= m;
        }
        __builtin_nontemporal_store(v, &out[idx4]);
    }
}

extern "C" void kernel_launch(void* const* d_in, const int* in_sizes, int n_in,
                              void* d_out, int out_size, void* d_ws, size_t ws_size,
                              hipStream_t stream) {
    const float* data = (const float*)d_in[0];
    const int* a_idx  = (const int*)d_in[1];
    const int* a_len  = (const int*)d_in[2];
    const int* s_len  = (const int*)d_in[3];
    float* out        = (float*)d_out;

    const int B = out_size / (kL * 100);      // 512
    const int blocks = B * 2;                 // 1024: one per (b, half)
    const int threads = 256;

    mask_mul_kernel<<<blocks, threads, 0, stream>>>(
        (const f32x4*)data, a_idx, a_len, s_len, (f32x4*)out);
}